// Round 2
// baseline (2407.795 us; speedup 1.0000x reference)
//
#include <hip/hip_runtime.h>

typedef unsigned short u16;
typedef float f32x4 __attribute__((ext_vector_type(4)));
typedef short s16x8 __attribute__((ext_vector_type(8)));
typedef unsigned short u16x4 __attribute__((ext_vector_type(4)));

__device__ __forceinline__ u16 f2b(float x){
  union{float f; unsigned u;} a; a.f=x;
  return (u16)((a.u + 0x7fffu + ((a.u>>16)&1u))>>16);
}

__device__ __forceinline__ float block_reduce(float v, int op, float* sh){
  #pragma unroll
  for (int o=32;o>0;o>>=1){
    float t = __shfl_down(v, o);
    v = op ? fmaxf(v,t) : v+t;
  }
  int w = threadIdx.x>>6;
  if ((threadIdx.x&63)==0) sh[w]=v;
  __syncthreads();
  float r = op ? fmaxf(fmaxf(sh[0],sh[1]),fmaxf(sh[2],sh[3]))
               : (sh[0]+sh[1]+sh[2]+sh[3]);
  __syncthreads();
  return r;
}

// ---------------------------------------------------------------------------
// NT GEMM: C[m][n] = sum_k A[m][k] * B[n][k]  (+bias[n]) with optional row
// gather on A and/or B. Tiles 128x128, BK=64, 256 threads (4 waves, each a
// 64x64 quadrant as 4x4 fragments of mfma_f32_16x16x32_bf16).
// z-batched: operand offset = (z/zd)*s1 + (z%zd)*s2.
// EPI: 0 = bf16 store, 1 = sqrelu->bf16, 2 = f32 residual +=, 3 = f32 store,
//      4 = transposed bf16 store: C[(m/mb)*cbatch + n*ldc + m%mb]
// ---------------------------------------------------------------------------
template<int EPI, bool AG, bool BG>
__global__ __launch_bounds__(256)
void gemm_nt(const u16* __restrict__ A, const int* __restrict__ aidx,
             long a_s1, long a_s2, int azd, int lda,
             const u16* __restrict__ B, const int* __restrict__ bidx,
             long b_s1, long b_s2, int bzd, int ldb,
             const float* __restrict__ bias,
             void* __restrict__ Cv, long c_s1, long c_s2, int czd, int ldc,
             int K, int mb, long cbatch)
{
  __shared__ u16 lA[128][72];
  __shared__ u16 lB[128][72];
  const int tid = threadIdx.x;
  const int z = blockIdx.z;
  const int m0 = blockIdx.x * 128;
  const int n0 = blockIdx.y * 128;
  const u16* Ab = A + (long)(z/azd)*a_s1 + (long)(z%azd)*a_s2;
  const u16* Bb = B + (long)(z/bzd)*b_s1 + (long)(z%bzd)*b_s2;

  const int w = tid >> 6, lane = tid & 63;
  const int wr = w >> 1, wc = w & 1;
  const int lm = lane >> 4, ln = lane & 15;

  f32x4 acc[4][4];
  #pragma unroll
  for (int i=0;i<4;i++)
    #pragma unroll
    for (int j=0;j<4;j++) acc[i][j] = (f32x4){0.f,0.f,0.f,0.f};

  for (int kt = 0; kt < K; kt += 64) {
    __syncthreads();
    #pragma unroll
    for (int i = 0; i < 4; i++) {
      int c = tid + i*256;
      int r = c >> 3, kc = (c & 7) << 3;
      long arow = AG ? (long)aidx[m0 + r] : (long)(m0 + r);
      s16x8 va = *(const s16x8*)(Ab + arow*(long)lda + kt + kc);
      *(s16x8*)(&lA[r][kc]) = va;
      long brow = BG ? (long)bidx[n0 + r] : (long)(n0 + r);
      s16x8 vb = *(const s16x8*)(Bb + brow*(long)ldb + kt + kc);
      *(s16x8*)(&lB[r][kc]) = vb;
    }
    __syncthreads();
    #pragma unroll
    for (int kk = 0; kk < 2; kk++) {
      const int ks = kk*32 + lm*8;
      s16x8 af[4], bf[4];
      #pragma unroll
      for (int i=0;i<4;i++) af[i] = *(const s16x8*)(&lA[wr*64 + i*16 + ln][ks]);
      #pragma unroll
      for (int j=0;j<4;j++) bf[j] = *(const s16x8*)(&lB[wc*64 + j*16 + ln][ks]);
      #pragma unroll
      for (int i=0;i<4;i++)
        #pragma unroll
        for (int j=0;j<4;j++)
          acc[i][j] = __builtin_amdgcn_mfma_f32_16x16x32_bf16(af[i], bf[j], acc[i][j], 0,0,0);
    }
  }

  const long co = (long)(z/czd)*c_s1 + (long)(z%czd)*c_s2;
  #pragma unroll
  for (int i=0;i<4;i++) {
    const int gmb = m0 + wr*64 + i*16 + lm*4;
    #pragma unroll
    for (int j=0;j<4;j++) {
      const int gn = n0 + wc*64 + j*16 + ln;
      float bb = 0.f;
      if constexpr (EPI != 3) { if (bias) bb = bias[gn]; }
      f32x4 v = acc[i][j];
      if constexpr (EPI == 4) {
        long addr = co + (long)(gmb/mb)*cbatch + (long)gn*ldc + (gmb%mb);
        u16x4 pk;
        #pragma unroll
        for (int r=0;r<4;r++) pk[r] = f2b(v[r] + bb);
        *(u16x4*)((u16*)Cv + addr) = pk;
      } else if constexpr (EPI == 2) {
        float* Cf = (float*)Cv;
        #pragma unroll
        for (int r=0;r<4;r++) {
          long idx = co + (long)(gmb+r)*ldc + gn;
          Cf[idx] += v[r] + bb;
        }
      } else if constexpr (EPI == 3) {
        float* Cf = (float*)Cv;
        #pragma unroll
        for (int r=0;r<4;r++) Cf[co + (long)(gmb+r)*ldc + gn] = v[r];
      } else {
        u16* Cb = (u16*)Cv;
        #pragma unroll
        for (int r=0;r<4;r++) {
          float x = v[r] + bb;
          if constexpr (EPI == 1) { x = x > 0.f ? x*x : 0.f; }
          Cb[co + (long)(gmb+r)*ldc + gn] = f2b(x);
        }
      }
    }
  }
}

// ---------------------------------------------------------------------------
// LayerNorm of a 1024-wide f32 row -> bf16 (optionally two gain/bias sets).
// ---------------------------------------------------------------------------
template<int TWO>
__global__ __launch_bounds__(256)
void ln_kernel(const float* __restrict__ X,
               const float* __restrict__ g1, const float* __restrict__ bb1,
               const float* __restrict__ g2, const float* __restrict__ bb2,
               u16* __restrict__ o1, u16* __restrict__ o2)
{
  __shared__ float sh[4];
  const long row = blockIdx.x;
  const int tid = threadIdx.x;
  const float* x = X + row*1024;
  float4 t = *(const float4*)(x + tid*4);
  float s = t.x+t.y+t.z+t.w;
  float m = block_reduce(s, 0, sh) * (1.f/1024.f);
  float d0=t.x-m, d1=t.y-m, d2=t.z-m, d3=t.w-m;
  float s2 = d0*d0+d1*d1+d2*d2+d3*d3;
  float var = block_reduce(s2, 0, sh) * (1.f/1024.f);
  float r = rsqrtf(var + 1e-5f);
  const int c = tid*4;
  {
    float4 g = *(const float4*)(g1+c);
    float4 b = *(const float4*)(bb1+c);
    u16x4 pk;
    pk[0]=f2b(d0*r*g.x+b.x); pk[1]=f2b(d1*r*g.y+b.y);
    pk[2]=f2b(d2*r*g.z+b.z); pk[3]=f2b(d3*r*g.w+b.w);
    *(u16x4*)(o1 + row*1024 + c) = pk;
  }
  if constexpr (TWO) {
    float4 g = *(const float4*)(g2+c);
    float4 b = *(const float4*)(bb2+c);
    u16x4 pk;
    pk[0]=f2b(d0*r*g.x+b.x); pk[1]=f2b(d1*r*g.y+b.y);
    pk[2]=f2b(d2*r*g.z+b.z); pk[3]=f2b(d3*r*g.w+b.w);
    *(u16x4*)(o2 + row*1024 + c) = pk;
  }
}

// ---------------------------------------------------------------------------
// Masked softmax over a row of LEN f32 scores; writes bf16 P in place
// (row-local: first LEN bf16 of the same row's storage). allowed j <= off+qi.
// ---------------------------------------------------------------------------
template<int LEN>
__global__ __launch_bounds__(256)
void softmax_k(float* __restrict__ S, int qmask, int off, float scale)
{
  constexpr int PER = LEN/256;
  __shared__ float sh[4];
  const long row = blockIdx.x;
  const int qi = ((int)row) & qmask;
  const int lim = off + qi;
  float* srow = S + row*(long)LEN;
  const int tid = threadIdx.x;
  float v[PER];
  float mx = -3.0e38f;
  #pragma unroll
  for (int i=0;i<PER/4;i++){
    int j0 = i*1024 + tid*4;
    float4 t = *(const float4*)(srow + j0);
    float tv[4] = {t.x,t.y,t.z,t.w};
    #pragma unroll
    for (int k=0;k<4;k++){
      float val = (j0+k <= lim) ? tv[k]*scale : -3.0e38f;
      v[i*4+k] = val;
      mx = fmaxf(mx, val);
    }
  }
  float M = block_reduce(mx, 1, sh);
  float s = 0.f;
  #pragma unroll
  for (int i=0;i<PER;i++){ float e = __expf(v[i]-M); v[i]=e; s+=e; }
  float T = block_reduce(s, 0, sh);
  float inv = 1.0f / T;
  u16* p = (u16*)srow;
  #pragma unroll
  for (int i=0;i<PER/4;i++){
    int j0 = i*1024 + tid*4;
    u16x4 pk;
    #pragma unroll
    for (int k=0;k<4;k++) pk[k] = f2b(v[i*4+k]*inv);
    *(u16x4*)(p + j0) = pk;
  }
}

// ---------------------------------------------------------------------------
// z init: z[b,q,:] = emb[inputs[b, 7168+q], :] (f32).
// ---------------------------------------------------------------------------
__global__ __launch_bounds__(256)
void zinit(const int* __restrict__ inputs, const float* __restrict__ emb,
           float* __restrict__ z)
{
  const int row = blockIdx.x;            // 0..4095
  const int b = row >> 10, q = row & 1023;
  const int id = inputs[(long)b*8192 + 7168 + q];
  float4 v = *(const float4*)(emb + (long)id*1024 + threadIdx.x*4);
  *(float4*)(z + (long)row*1024 + threadIdx.x*4) = v;
}

// ---------------------------------------------------------------------------
// Transpose all 18 weight matrices f32 (k,n) -> bf16 (n,k), 32x32 LDS tiles.
// slots: 0..5 = c_{wq,wk,wv,wo,w1,w2}; 6+l*6+j = s_{wq,wk,wv,wo,w1,w2}[l]
// ---------------------------------------------------------------------------
__global__ __launch_bounds__(256)
void transpose_w(const float* cwq, const float* cwk, const float* cwv,
                 const float* cwo, const float* cw1, const float* cw2,
                 const float* swq, const float* swk, const float* swv,
                 const float* swo, const float* sw1, const float* sw2,
                 u16* __restrict__ wT)
{
  const int slot = blockIdx.z;
  const float* W;
  switch (slot) {
    case 0:  W = cwq; break;  case 1:  W = cwk; break;
    case 2:  W = cwv; break;  case 3:  W = cwo; break;
    case 4:  W = cw1; break;  case 5:  W = cw2; break;
    case 6:  W = swq; break;  case 7:  W = swk; break;
    case 8:  W = swv; break;  case 9:  W = swo; break;
    case 10: W = sw1; break;  case 11: W = sw2; break;
    case 12: W = swq + 1048576; break; case 13: W = swk + 1048576; break;
    case 14: W = swv + 1048576; break; case 15: W = swo + 1048576; break;
    case 16: W = sw1 + 1048576; break; default: W = sw2 + 1048576; break;
  }
  u16* T = wT + (long)slot*1048576;
  __shared__ float t[32][33];
  const int tx = threadIdx.x & 31, ty = threadIdx.x >> 5;   // 32 x 8
  const int k0 = blockIdx.x*32, n0 = blockIdx.y*32;
  #pragma unroll
  for (int i=0;i<4;i++)
    t[ty + i*8][tx] = W[(long)(k0 + ty + i*8)*1024 + n0 + tx];
  __syncthreads();
  #pragma unroll
  for (int i=0;i<4;i++)
    T[(long)(n0 + ty + i*8)*1024 + k0 + tx] = f2b(t[tx][ty + i*8]);
}

// ---------------------------------------------------------------------------
extern "C" void kernel_launch(void* const* d_in, const int* in_sizes, int n_in,
                              void* d_out, int out_size, void* d_ws, size_t ws_size,
                              hipStream_t stream)
{
  (void)in_sizes; (void)n_in; (void)out_size;
  const int*   inputs   = (const int*)  d_in[0];
  const float* emb      = (const float*)d_in[1];
  const float* c_lnq_g  = (const float*)d_in[2];
  const float* c_lnq_b  = (const float*)d_in[3];
  const float* c_lnkv_g = (const float*)d_in[4];
  const float* c_lnkv_b = (const float*)d_in[5];
  const float* c_bq = (const float*)d_in[7];
  const float* c_bk = (const float*)d_in[9];
  const float* c_bv = (const float*)d_in[11];
  const float* c_bo = (const float*)d_in[13];
  const float* c_ln2_g = (const float*)d_in[14];
  const float* c_ln2_b = (const float*)d_in[15];
  const float* c_b1 = (const float*)d_in[17];
  const float* c_b2 = (const float*)d_in[19];
  const float* s_lnq_g = (const float*)d_in[20];
  const float* s_lnq_b = (const float*)d_in[21];
  const float* s_bq = (const float*)d_in[23];
  const float* s_bk = (const float*)d_in[25];
  const float* s_bv = (const float*)d_in[27];
  const float* s_bo = (const float*)d_in[29];
  const float* s_ln2_g = (const float*)d_in[30];
  const float* s_ln2_b = (const float*)d_in[31];
  const float* s_b1 = (const float*)d_in[33];
  const float* s_b2 = (const float*)d_in[35];

  const long MB1 = 1048576;

  char* wsb = (char*)d_ws;
  size_t off = 0;
  auto alloc = [&](size_t n)->char* {
    char* p = wsb + off; off += (n + 255) & ~(size_t)255; return p;
  };
  u16*   wT       = (u16*)  alloc((size_t)18*1048576*2);   // 36 MB
  u16*   lnkv_tab = (u16*)  alloc((size_t)8192*1024*2);    // 16 MB
  u16*   Ktab     = (u16*)  alloc((size_t)8192*1024*2);    // 16 MB
  u16*   VTcb     = (u16*)  alloc((size_t)1024*8192*2);    // 16 MB (per-b, reused)
  u16*   Q        = (u16*)  alloc((size_t)4096*1024*2);    // 8 MB
  u16*   zn       = (u16*)  alloc((size_t)4096*1024*2);
  u16*   h1       = (u16*)  alloc((size_t)4096*1024*2);
  u16*   O        = (u16*)  alloc((size_t)4096*1024*2);
  u16*   Qs       = (u16*)  alloc((size_t)4096*1024*2);
  u16*   Ks       = (u16*)  alloc((size_t)4096*1024*2);
  u16*   VsT      = (u16*)  alloc((size_t)4096*1024*2);
  float* scores   = (float*)alloc((size_t)8*1024*1024*4);  // 32 MB (reused)
  float* z        = (float*)d_out;                         // residual lives in d_out

  if (ws_size < off) return;  // ws too small: leave output zeroed (diagnostic)

  // ---- setup -------------------------------------------------------------
  transpose_w<<<dim3(32,32,18), 256, 0, stream>>>(
      (const float*)d_in[6], (const float*)d_in[8], (const float*)d_in[10],
      (const float*)d_in[12], (const float*)d_in[16], (const float*)d_in[18],
      (const float*)d_in[22], (const float*)d_in[24], (const float*)d_in[26],
      (const float*)d_in[28], (const float*)d_in[32], (const float*)d_in[34], wT);
  ln_kernel<0><<<8192, 256, 0, stream>>>(emb, c_lnkv_g, c_lnkv_b,
                                         nullptr, nullptr, lnkv_tab, nullptr);
  zinit<<<4096, 256, 0, stream>>>(inputs, emb, z);
  // zn = LN(z) with c_lnq  (z == gathered emb rows)
  ln_kernel<0><<<4096, 256, 0, stream>>>(z, c_lnq_g, c_lnq_b,
                                         nullptr, nullptr, zn, nullptr);

  // ---- cross attention ---------------------------------------------------
  // Ktab = LNkv(emb_vocab) @ wk^T + bk   (per-vocab table)
  gemm_nt<0,false,false><<<dim3(64,8,1),256,0,stream>>>(
      lnkv_tab, nullptr, 0,0,1, 1024,
      wT + 1*MB1, nullptr, 0,0,1, 1024,
      c_bk, Ktab, 0,0,1, 1024, 1024, 1, 0);
  // Q = zn @ wq^T + bq
  gemm_nt<0,false,false><<<dim3(32,8,1),256,0,stream>>>(
      zn, nullptr, 0,0,1, 1024,
      wT + 0*MB1, nullptr, 0,0,1, 1024,
      c_bq, Q, 0,0,1, 1024, 1024, 1, 0);
  for (int b = 0; b < 4; ++b) {
    // VTcb[d][s] = (gather_b(lnkv_tab) @ wv^T + bv)^T
    gemm_nt<4,true,false><<<dim3(64,8,1),256,0,stream>>>(
        lnkv_tab, inputs + (long)b*8192, 0,0,1, 1024,
        wT + 2*MB1, nullptr, 0,0,1, 1024,
        c_bv, VTcb, 0,0,1, 8192, 1024, 8192, 0);
    // scores = Q_b @ gather_b(Ktab)^T   (f32, 1024 x 8192)
    gemm_nt<3,false,true><<<dim3(8,64,1),256,0,stream>>>(
        Q + (long)b*MB1, nullptr, 0,0,1, 1024,
        Ktab, inputs + (long)b*8192, 0,0,1, 1024,
        nullptr, scores, 0,0,1, 8192, 1024, 1, 0);
    softmax_k<8192><<<1024, 256, 0, stream>>>(scores, 1023, 7168, 1.0f/32.0f);
    // O_b = P @ V  (NT against VTcb), P read in place as bf16 (lda = 2*8192)
    gemm_nt<0,false,false><<<dim3(8,8,1),256,0,stream>>>(
        (const u16*)scores, nullptr, 0,0,1, 16384,
        VTcb, nullptr, 0,0,1, 8192,
        nullptr, O + (long)b*MB1, 0,0,1, 1024, 8192, 1, 0);
  }
  // z += O @ wo^T + bo
  gemm_nt<2,false,false><<<dim3(32,8,1),256,0,stream>>>(
      O, nullptr, 0,0,1, 1024,
      wT + 3*MB1, nullptr, 0,0,1, 1024,
      c_bo, z, 0,0,1, 1024, 1024, 1, 0);

  // ---- central FFN -------------------------------------------------------
  ln_kernel<0><<<4096,256,0,stream>>>(z, c_ln2_g, c_ln2_b, nullptr,nullptr, zn, nullptr);
  gemm_nt<1,false,false><<<dim3(32,8,1),256,0,stream>>>(
      zn, nullptr, 0,0,1, 1024,
      wT + 4*MB1, nullptr, 0,0,1, 1024,
      c_b1, h1, 0,0,1, 1024, 1024, 1, 0);
  gemm_nt<2,false,false><<<dim3(32,8,1),256,0,stream>>>(
      h1, nullptr, 0,0,1, 1024,
      wT + 5*MB1, nullptr, 0,0,1, 1024,
      c_b2, z, 0,0,1, 1024, 1024, 1, 0);

  // ---- self-attention blocks (NB*L = 4, l = 0,1,0,1) ---------------------
  for (int it = 0; it < 4; ++it) {
    const int l = it & 1;
    const u16* wq = wT + (size_t)(6 + l*6 + 0)*MB1;
    const u16* wk = wT + (size_t)(6 + l*6 + 1)*MB1;
    const u16* wv = wT + (size_t)(6 + l*6 + 2)*MB1;
    const u16* wo = wT + (size_t)(6 + l*6 + 3)*MB1;
    const u16* w1 = wT + (size_t)(6 + l*6 + 4)*MB1;
    const u16* w2 = wT + (size_t)(6 + l*6 + 5)*MB1;

    ln_kernel<0><<<4096,256,0,stream>>>(z, s_lnq_g + l*1024, s_lnq_b + l*1024,
                                        nullptr,nullptr, zn, nullptr);
    gemm_nt<0,false,false><<<dim3(32,8,1),256,0,stream>>>(
        zn, nullptr, 0,0,1, 1024,  wq, nullptr, 0,0,1, 1024,
        s_bq + l*1024, Qs, 0,0,1, 1024, 1024, 1, 0);
    gemm_nt<0,false,false><<<dim3(32,8,1),256,0,stream>>>(
        zn, nullptr, 0,0,1, 1024,  wk, nullptr, 0,0,1, 1024,
        s_bk + l*1024, Ks, 0,0,1, 1024, 1024, 1, 0);
    // VsT[b][d][q]
    gemm_nt<4,false,false><<<dim3(32,8,1),256,0,stream>>>(
        zn, nullptr, 0,0,1, 1024,  wv, nullptr, 0,0,1, 1024,
        s_bv + l*1024, VsT, 0,0,1, 1024, 1024, 1024, MB1);
    for (int b = 0; b < 4; ++b) {
      // scores[h] = Q_bh @ K_bh^T   (K = 128), 8 heads of this batch
      gemm_nt<3,false,false><<<dim3(8,8,8),256,0,stream>>>(
          Qs + (long)b*MB1, nullptr, 0,128,8, 1024,
          Ks + (long)b*MB1, nullptr, 0,128,8, 1024,
          nullptr, scores, MB1,0,1, 1024, 128, 1, 0);
      softmax_k<1024><<<8192, 256, 0, stream>>>(scores, 1023, 0, 0.08838834764831845f);
      // O_bh = P_h @ V_bh  (NT against VsT), P in place (lda = 2*1024)
      gemm_nt<0,false,false><<<dim3(8,1,8),256,0,stream>>>(
          (const u16*)scores, nullptr, 2097152,0,1, 2048,
          VsT + (long)b*MB1, nullptr, 0,131072,8, 1024,
          nullptr, O + (long)b*MB1, 0,128,8, 1024, 1024, 1, 0);
    }
    gemm_nt<2,false,false><<<dim3(32,8,1),256,0,stream>>>(
        O, nullptr, 0,0,1, 1024,  wo, nullptr, 0,0,1, 1024,
        s_bo + l*1024, z, 0,0,1, 1024, 1024, 1, 0);

    ln_kernel<0><<<4096,256,0,stream>>>(z, s_ln2_g + l*1024, s_ln2_b + l*1024,
                                        nullptr,nullptr, zn, nullptr);
    gemm_nt<1,false,false><<<dim3(32,8,1),256,0,stream>>>(
        zn, nullptr, 0,0,1, 1024,  w1, nullptr, 0,0,1, 1024,
        s_b1 + l*1024, h1, 0,0,1, 1024, 1024, 1, 0);
    gemm_nt<2,false,false><<<dim3(32,8,1),256,0,stream>>>(
        h1, nullptr, 0,0,1, 1024,  w2, nullptr, 0,0,1, 1024,
        s_b2 + l*1024, z, 0,0,1, 1024, 1024, 1, 0);
  }
}

// Round 3
// 1548.154 us; speedup vs baseline: 1.5553x; 1.5553x over previous
//
#include <hip/hip_runtime.h>

typedef unsigned short u16;
typedef float f32x4 __attribute__((ext_vector_type(4)));
typedef short s16x8 __attribute__((ext_vector_type(8)));
typedef unsigned short u16x4 __attribute__((ext_vector_type(4)));

__device__ __forceinline__ u16 f2b(float x){
  union{float f; unsigned u;} a; a.f=x;
  return (u16)((a.u + 0x7fffu + ((a.u>>16)&1u))>>16);
}

__device__ __forceinline__ float block_reduce(float v, int op, float* sh){
  #pragma unroll
  for (int o=32;o>0;o>>=1){
    float t = __shfl_down(v, o);
    v = op ? fmaxf(v,t) : v+t;
  }
  int w = threadIdx.x>>6;
  if ((threadIdx.x&63)==0) sh[w]=v;
  __syncthreads();
  float r = op ? fmaxf(fmaxf(sh[0],sh[1]),fmaxf(sh[2],sh[3]))
               : (sh[0]+sh[1]+sh[2]+sh[3]);
  __syncthreads();
  return r;
}

// ---------------------------------------------------------------------------
// NT GEMM: C[m][n] = sum_k A[m][k] * B[n][k]  (+bias[n]) with optional row
// gather on A and/or B. Tiles 128x128, BK=64, 256 threads (4 waves).
// z-batched: operand offset = (z/zd)*s1 + (z%zd)*s2.
// EPI: 0 = bf16 store, 1 = sqrelu->bf16, 2 = f32 residual +=, 3 = f32 store,
//      4 = transposed bf16 store: C[(m/mb)*cbatch + n*ldc + m%mb]
// ---------------------------------------------------------------------------
template<int EPI, bool AG, bool BG>
__global__ __launch_bounds__(256)
void gemm_nt(const u16* __restrict__ A, const int* __restrict__ aidx,
             long a_s1, long a_s2, int azd, int lda,
             const u16* __restrict__ B, const int* __restrict__ bidx,
             long b_s1, long b_s2, int bzd, int ldb,
             const float* __restrict__ bias,
             void* __restrict__ Cv, long c_s1, long c_s2, int czd, int ldc,
             int K, int mb, long cbatch)
{
  __shared__ u16 lA[128][72];
  __shared__ u16 lB[128][72];
  const int tid = threadIdx.x;
  const int z = blockIdx.z;
  const int m0 = blockIdx.x * 128;
  const int n0 = blockIdx.y * 128;
  const u16* Ab = A + (long)(z/azd)*a_s1 + (long)(z%azd)*a_s2;
  const u16* Bb = B + (long)(z/bzd)*b_s1 + (long)(z%bzd)*b_s2;

  const int w = tid >> 6, lane = tid & 63;
  const int wr = w >> 1, wc = w & 1;
  const int lm = lane >> 4, ln = lane & 15;

  f32x4 acc[4][4];
  #pragma unroll
  for (int i=0;i<4;i++)
    #pragma unroll
    for (int j=0;j<4;j++) acc[i][j] = (f32x4){0.f,0.f,0.f,0.f};

  for (int kt = 0; kt < K; kt += 64) {
    __syncthreads();
    #pragma unroll
    for (int i = 0; i < 4; i++) {
      int c = tid + i*256;
      int r = c >> 3, kc = (c & 7) << 3;
      long arow = AG ? (long)aidx[m0 + r] : (long)(m0 + r);
      s16x8 va = *(const s16x8*)(Ab + arow*(long)lda + kt + kc);
      *(s16x8*)(&lA[r][kc]) = va;
      long brow = BG ? (long)bidx[n0 + r] : (long)(n0 + r);
      s16x8 vb = *(const s16x8*)(Bb + brow*(long)ldb + kt + kc);
      *(s16x8*)(&lB[r][kc]) = vb;
    }
    __syncthreads();
    #pragma unroll
    for (int kk = 0; kk < 2; kk++) {
      const int ks = kk*32 + lm*8;
      s16x8 af[4], bf[4];
      #pragma unroll
      for (int i=0;i<4;i++) af[i] = *(const s16x8*)(&lA[wr*64 + i*16 + ln][ks]);
      #pragma unroll
      for (int j=0;j<4;j++) bf[j] = *(const s16x8*)(&lB[wc*64 + j*16 + ln][ks]);
      #pragma unroll
      for (int i=0;i<4;i++)
        #pragma unroll
        for (int j=0;j<4;j++)
          acc[i][j] = __builtin_amdgcn_mfma_f32_16x16x32_bf16(af[i], bf[j], acc[i][j], 0,0,0);
    }
  }

  const long co = (long)(z/czd)*c_s1 + (long)(z%czd)*c_s2;
  #pragma unroll
  for (int i=0;i<4;i++) {
    const int gmb = m0 + wr*64 + i*16 + lm*4;
    #pragma unroll
    for (int j=0;j<4;j++) {
      const int gn = n0 + wc*64 + j*16 + ln;
      float bb = 0.f;
      if constexpr (EPI != 3) { if (bias) bb = bias[gn]; }
      f32x4 v = acc[i][j];
      if constexpr (EPI == 4) {
        long addr = co + (long)(gmb/mb)*cbatch + (long)gn*ldc + (gmb%mb);
        u16x4 pk;
        #pragma unroll
        for (int r=0;r<4;r++) pk[r] = f2b(v[r] + bb);
        *(u16x4*)((u16*)Cv + addr) = pk;
      } else if constexpr (EPI == 2) {
        float* Cf = (float*)Cv;
        #pragma unroll
        for (int r=0;r<4;r++) {
          long idx = co + (long)(gmb+r)*ldc + gn;
          Cf[idx] += v[r] + bb;
        }
      } else if constexpr (EPI == 3) {
        float* Cf = (float*)Cv;
        #pragma unroll
        for (int r=0;r<4;r++) Cf[co + (long)(gmb+r)*ldc + gn] = v[r];
      } else {
        u16* Cb = (u16*)Cv;
        #pragma unroll
        for (int r=0;r<4;r++) {
          float x = v[r] + bb;
          if constexpr (EPI == 1) { x = x > 0.f ? x*x : 0.f; }
          Cb[co + (long)(gmb+r)*ldc + gn] = f2b(x);
        }
      }
    }
  }
}

// ---------------------------------------------------------------------------
// Flash self-attention: causal, H=8, d=128, Z=1024 per batch.
// Grid (8 q-tiles, 32 b*h). Block 256 thr, 4 waves; wave owns 32 q-rows.
// Computes S^T = K·Q^T per KV-tile of 64 (so the row-softmax is per-lane),
// P goes through per-wave XOR-swizzled LDS, PV consumes V^T (from VsT).
// ---------------------------------------------------------------------------
__global__ __launch_bounds__(256)
void flash_self(const u16* __restrict__ Qs, const u16* __restrict__ Ks,
                const u16* __restrict__ VsT, u16* __restrict__ O)
{
  __shared__ u16 lK[64][128];    // [kk][d], 16B-chunk XOR swizzle
  __shared__ u16 lV[128][64];    // [d][kk], swizzled
  __shared__ u16 lP[4][32][64];  // per-wave [q][kk], swizzled

  const int tid = threadIdx.x;
  const int w = tid >> 6, lane = tid & 63;
  const int g = lane >> 4, ln = lane & 15;
  const int bx = blockIdx.x;
  const int b  = blockIdx.y >> 3, h = blockIdx.y & 7;

  const long qrow0 = (long)b*1024 + bx*128 + w*32;
  const u16* Qp = Qs + qrow0*1024 + h*128;
  const u16* Kp = Ks + (long)b*1048576 + h*128;
  const u16* Vp = VsT + (long)b*1048576 + (long)h*128*1024;

  // Q as B-operand frags: n=q=16*nj+ln, k(d) = 32*ks + 8*g + j
  s16x8 bq[2][4];
  #pragma unroll
  for (int nj=0;nj<2;nj++)
    #pragma unroll
    for (int ks=0;ks<4;ks++)
      bq[nj][ks] = *(const s16x8*)(Qp + (long)(16*nj + ln)*1024 + ks*32 + g*8);

  f32x4 ao[8][2];                // O^T acc: row d=16mi+4g+r, col q=16nj+ln
  #pragma unroll
  for (int i=0;i<8;i++)
    #pragma unroll
    for (int j=0;j<2;j++) ao[i][j] = (f32x4){0.f,0.f,0.f,0.f};
  float mrun[2] = {-3.0e38f, -3.0e38f};
  float lrun[2] = {0.f, 0.f};
  const int qc0 = bx*128 + w*32 + ln;

  const int nt = 2*bx + 2;
  for (int kt = 0; kt < nt; ++kt) {
    __syncthreads();
    {
      const u16* src = Kp + (long)(kt*64)*1024;
      #pragma unroll
      for (int i=0;i<4;i++){
        int c = i*256 + tid;
        int rr = c >> 4, d8 = c & 15;
        s16x8 v = *(const s16x8*)(src + (long)rr*1024 + d8*8);
        *(s16x8*)(&lK[rr][(d8 ^ (rr&7))*8]) = v;
      }
      const u16* vsrc = Vp + kt*64;
      #pragma unroll
      for (int i=0;i<4;i++){
        int c = i*256 + tid;
        int dd = c >> 3, k8 = c & 7;
        s16x8 v = *(const s16x8*)(vsrc + (long)dd*1024 + k8*8);
        *(s16x8*)(&lV[dd][(k8 ^ (dd&7))*8]) = v;
      }
    }
    __syncthreads();

    // S^T tile: rows kk (4 frags), cols q (2 frags)
    f32x4 as_[4][2];
    #pragma unroll
    for (int i=0;i<4;i++)
      #pragma unroll
      for (int j=0;j<2;j++) as_[i][j] = (f32x4){0.f,0.f,0.f,0.f};
    #pragma unroll
    for (int ks=0;ks<4;ks++){
      s16x8 ak[4];
      #pragma unroll
      for (int mi=0;mi<4;mi++)
        ak[mi] = *(const s16x8*)(&lK[16*mi + ln][((g + 4*ks) ^ (ln&7))*8]);
      #pragma unroll
      for (int mi=0;mi<4;mi++)
        #pragma unroll
        for (int nj=0;nj<2;nj++)
          as_[mi][nj] = __builtin_amdgcn_mfma_f32_16x16x32_bf16(ak[mi], bq[nj][ks], as_[mi][nj], 0,0,0);
    }

    // online softmax per q-column (per lane + cross-g shfl)
    const int kkb = kt*64 + 4*g;
    #pragma unroll
    for (int nj=0;nj<2;nj++){
      const int qc = qc0 + 16*nj;
      float mx = -3.0e38f;
      #pragma unroll
      for (int mi=0;mi<4;mi++)
        #pragma unroll
        for (int r=0;r<4;r++){
          float s = as_[mi][nj][r] * 0.08838834764831845f;
          if (kkb + 16*mi + r > qc) s = -3.0e38f;
          as_[mi][nj][r] = s;
          mx = fmaxf(mx, s);
        }
      mx = fmaxf(mx, __shfl_xor(mx, 16));
      mx = fmaxf(mx, __shfl_xor(mx, 32));
      float mnew = fmaxf(mrun[nj], mx);
      float alpha = __expf(mrun[nj] - mnew);
      float sum = 0.f;
      #pragma unroll
      for (int mi=0;mi<4;mi++){
        u16x4 pk;
        #pragma unroll
        for (int r=0;r<4;r++){
          float p = __expf(as_[mi][nj][r] - mnew);
          sum += p;
          pk[r] = f2b(p);
        }
        // P[q][kk]: q=16nj+ln, kk=16mi+4g .. +3 ; 16B-granule swizzle by q&7
        *(u16x4*)(&lP[w][16*nj + ln][(((2*mi + (g>>1)) ^ (ln&7))<<3) + (g&1)*4]) = pk;
      }
      sum += __shfl_xor(sum, 16);
      sum += __shfl_xor(sum, 32);
      lrun[nj] = lrun[nj]*alpha + sum;
      mrun[nj] = mnew;
      #pragma unroll
      for (int mi=0;mi<8;mi++)
        #pragma unroll
        for (int r=0;r<4;r++)
          ao[mi][nj][r] *= alpha;
    }

    // O^T += V^T · P^T  (A from lV, B from lP)
    #pragma unroll
    for (int ks=0;ks<2;ks++){
      s16x8 bp[2];
      #pragma unroll
      for (int nj=0;nj<2;nj++)
        bp[nj] = *(const s16x8*)(&lP[w][16*nj + ln][((4*ks + g) ^ (ln&7))*8]);
      #pragma unroll
      for (int mi=0;mi<8;mi++){
        s16x8 av = *(const s16x8*)(&lV[16*mi + ln][((g + 4*ks) ^ (ln&7))*8]);
        #pragma unroll
        for (int nj=0;nj<2;nj++)
          ao[mi][nj] = __builtin_amdgcn_mfma_f32_16x16x32_bf16(av, bp[nj], ao[mi][nj], 0,0,0);
      }
    }
  }

  const float inv0 = 1.f/lrun[0], inv1 = 1.f/lrun[1];
  #pragma unroll
  for (int nj=0;nj<2;nj++){
    const float inv = nj ? inv1 : inv0;
    #pragma unroll
    for (int mi=0;mi<8;mi++){
      u16x4 pk;
      #pragma unroll
      for (int r=0;r<4;r++) pk[r] = f2b(ao[mi][nj][r]*inv);
      *(u16x4*)(O + (qrow0 + 16*nj + ln)*1024 + h*128 + 16*mi + 4*g) = pk;
    }
  }
}

// ---------------------------------------------------------------------------
// Sum 4 split-K partial planes (f32, 1M elems each) -> bf16.
// ---------------------------------------------------------------------------
__global__ __launch_bounds__(256)
void reduce4(const float* __restrict__ Pp, u16* __restrict__ Ob){
  long i = ((long)blockIdx.x*256 + threadIdx.x)*4;
  f32x4 a = *(const f32x4*)(Pp + i);
  f32x4 b = *(const f32x4*)(Pp + 1048576 + i);
  f32x4 c = *(const f32x4*)(Pp + 2097152 + i);
  f32x4 d = *(const f32x4*)(Pp + 3145728 + i);
  u16x4 pk;
  #pragma unroll
  for (int r=0;r<4;r++) pk[r] = f2b(a[r]+b[r]+c[r]+d[r]);
  *(u16x4*)(Ob + i) = pk;
}

// ---------------------------------------------------------------------------
// LayerNorm of a 1024-wide f32 row -> bf16.
// ---------------------------------------------------------------------------
template<int TWO>
__global__ __launch_bounds__(256)
void ln_kernel(const float* __restrict__ X,
               const float* __restrict__ g1, const float* __restrict__ bb1,
               const float* __restrict__ g2, const float* __restrict__ bb2,
               u16* __restrict__ o1, u16* __restrict__ o2)
{
  __shared__ float sh[4];
  const long row = blockIdx.x;
  const int tid = threadIdx.x;
  const float* x = X + row*1024;
  float4 t = *(const float4*)(x + tid*4);
  float s = t.x+t.y+t.z+t.w;
  float m = block_reduce(s, 0, sh) * (1.f/1024.f);
  float d0=t.x-m, d1=t.y-m, d2=t.z-m, d3=t.w-m;
  float s2 = d0*d0+d1*d1+d2*d2+d3*d3;
  float var = block_reduce(s2, 0, sh) * (1.f/1024.f);
  float r = rsqrtf(var + 1e-5f);
  const int c = tid*4;
  {
    float4 g = *(const float4*)(g1+c);
    float4 b = *(const float4*)(bb1+c);
    u16x4 pk;
    pk[0]=f2b(d0*r*g.x+b.x); pk[1]=f2b(d1*r*g.y+b.y);
    pk[2]=f2b(d2*r*g.z+b.z); pk[3]=f2b(d3*r*g.w+b.w);
    *(u16x4*)(o1 + row*1024 + c) = pk;
  }
  if constexpr (TWO) {
    float4 g = *(const float4*)(g2+c);
    float4 b = *(const float4*)(bb2+c);
    u16x4 pk;
    pk[0]=f2b(d0*r*g.x+b.x); pk[1]=f2b(d1*r*g.y+b.y);
    pk[2]=f2b(d2*r*g.z+b.z); pk[3]=f2b(d3*r*g.w+b.w);
    *(u16x4*)(o2 + row*1024 + c) = pk;
  }
}

// ---------------------------------------------------------------------------
// Masked softmax over a row of LEN f32 scores; writes bf16 P in place.
// ---------------------------------------------------------------------------
template<int LEN>
__global__ __launch_bounds__(256)
void softmax_k(float* __restrict__ S, int qmask, int off, float scale)
{
  constexpr int PER = LEN/256;
  __shared__ float sh[4];
  const long row = blockIdx.x;
  const int qi = ((int)row) & qmask;
  const int lim = off + qi;
  float* srow = S + row*(long)LEN;
  const int tid = threadIdx.x;
  float v[PER];
  float mx = -3.0e38f;
  #pragma unroll
  for (int i=0;i<PER/4;i++){
    int j0 = i*1024 + tid*4;
    float4 t = *(const float4*)(srow + j0);
    float tv[4] = {t.x,t.y,t.z,t.w};
    #pragma unroll
    for (int k=0;k<4;k++){
      float val = (j0+k <= lim) ? tv[k]*scale : -3.0e38f;
      v[i*4+k] = val;
      mx = fmaxf(mx, val);
    }
  }
  float M = block_reduce(mx, 1, sh);
  float s = 0.f;
  #pragma unroll
  for (int i=0;i<PER;i++){ float e = __expf(v[i]-M); v[i]=e; s+=e; }
  float T = block_reduce(s, 0, sh);
  float inv = 1.0f / T;
  u16* p = (u16*)srow;
  #pragma unroll
  for (int i=0;i<PER/4;i++){
    int j0 = i*1024 + tid*4;
    u16x4 pk;
    #pragma unroll
    for (int k=0;k<4;k++) pk[k] = f2b(v[i*4+k]*inv);
    *(u16x4*)(p + j0) = pk;
  }
}

// ---------------------------------------------------------------------------
__global__ __launch_bounds__(256)
void zinit(const int* __restrict__ inputs, const float* __restrict__ emb,
           float* __restrict__ z)
{
  const int row = blockIdx.x;            // 0..4095
  const int b = row >> 10, q = row & 1023;
  const int id = inputs[(long)b*8192 + 7168 + q];
  float4 v = *(const float4*)(emb + (long)id*1024 + threadIdx.x*4);
  *(float4*)(z + (long)row*1024 + threadIdx.x*4) = v;
}

// ---------------------------------------------------------------------------
__global__ __launch_bounds__(256)
void transpose_w(const float* cwq, const float* cwk, const float* cwv,
                 const float* cwo, const float* cw1, const float* cw2,
                 const float* swq, const float* swk, const float* swv,
                 const float* swo, const float* sw1, const float* sw2,
                 u16* __restrict__ wT)
{
  const int slot = blockIdx.z;
  const float* W;
  switch (slot) {
    case 0:  W = cwq; break;  case 1:  W = cwk; break;
    case 2:  W = cwv; break;  case 3:  W = cwo; break;
    case 4:  W = cw1; break;  case 5:  W = cw2; break;
    case 6:  W = swq; break;  case 7:  W = swk; break;
    case 8:  W = swv; break;  case 9:  W = swo; break;
    case 10: W = sw1; break;  case 11: W = sw2; break;
    case 12: W = swq + 1048576; break; case 13: W = swk + 1048576; break;
    case 14: W = swv + 1048576; break; case 15: W = swo + 1048576; break;
    case 16: W = sw1 + 1048576; break; default: W = sw2 + 1048576; break;
  }
  u16* T = wT + (long)slot*1048576;
  __shared__ float t[32][33];
  const int tx = threadIdx.x & 31, ty = threadIdx.x >> 5;   // 32 x 8
  const int k0 = blockIdx.x*32, n0 = blockIdx.y*32;
  #pragma unroll
  for (int i=0;i<4;i++)
    t[ty + i*8][tx] = W[(long)(k0 + ty + i*8)*1024 + n0 + tx];
  __syncthreads();
  #pragma unroll
  for (int i=0;i<4;i++)
    T[(long)(n0 + ty + i*8)*1024 + k0 + tx] = f2b(t[tx][ty + i*8]);
}

// ---------------------------------------------------------------------------
extern "C" void kernel_launch(void* const* d_in, const int* in_sizes, int n_in,
                              void* d_out, int out_size, void* d_ws, size_t ws_size,
                              hipStream_t stream)
{
  (void)in_sizes; (void)n_in; (void)out_size;
  const int*   inputs   = (const int*)  d_in[0];
  const float* emb      = (const float*)d_in[1];
  const float* c_lnq_g  = (const float*)d_in[2];
  const float* c_lnq_b  = (const float*)d_in[3];
  const float* c_lnkv_g = (const float*)d_in[4];
  const float* c_lnkv_b = (const float*)d_in[5];
  const float* c_bq = (const float*)d_in[7];
  const float* c_bk = (const float*)d_in[9];
  const float* c_bv = (const float*)d_in[11];
  const float* c_bo = (const float*)d_in[13];
  const float* c_ln2_g = (const float*)d_in[14];
  const float* c_ln2_b = (const float*)d_in[15];
  const float* c_b1 = (const float*)d_in[17];
  const float* c_b2 = (const float*)d_in[19];
  const float* s_lnq_g = (const float*)d_in[20];
  const float* s_lnq_b = (const float*)d_in[21];
  const float* s_bq = (const float*)d_in[23];
  const float* s_bk = (const float*)d_in[25];
  const float* s_bv = (const float*)d_in[27];
  const float* s_bo = (const float*)d_in[29];
  const float* s_ln2_g = (const float*)d_in[30];
  const float* s_ln2_b = (const float*)d_in[31];
  const float* s_b1 = (const float*)d_in[33];
  const float* s_b2 = (const float*)d_in[35];

  const long MB1 = 1048576;

  char* wsb = (char*)d_ws;
  size_t off = 0;
  auto alloc = [&](size_t n)->char* {
    char* p = wsb + off; off += (n + 255) & ~(size_t)255; return p;
  };
  u16*   wT       = (u16*)  alloc((size_t)18*1048576*2);   // 36 MB
  u16*   lnkv_tab = (u16*)  alloc((size_t)8192*1024*2);    // 16 MB
  u16*   Ktab     = (u16*)  alloc((size_t)8192*1024*2);    // 16 MB
  u16*   VTcb     = (u16*)  alloc((size_t)1024*8192*2);    // 16 MB (per-b, reused)
  u16*   Q        = (u16*)  alloc((size_t)4096*1024*2);    // 8 MB
  u16*   zn       = (u16*)  alloc((size_t)4096*1024*2);
  u16*   h1       = (u16*)  alloc((size_t)4096*1024*2);
  u16*   O        = (u16*)  alloc((size_t)4096*1024*2);
  u16*   Qs       = (u16*)  alloc((size_t)4096*1024*2);    // 8 MB  (also Opart lo)
  u16*   Ks       = (u16*)  alloc((size_t)4096*1024*2);    // 8 MB  (also Opart hi)
  u16*   VsT      = (u16*)  alloc((size_t)4096*1024*2);
  float* scores   = (float*)alloc((size_t)8*1024*1024*4);  // 32 MB (reused)
  float* Opart    = (float*)Qs;   // 16 MB alias over Qs+Ks (dead during cross)
  float* z        = (float*)d_out;

  if (ws_size < off) return;  // ws too small: leave output zeroed (diagnostic)

  // ---- setup -------------------------------------------------------------
  transpose_w<<<dim3(32,32,18), 256, 0, stream>>>(
      (const float*)d_in[6], (const float*)d_in[8], (const float*)d_in[10],
      (const float*)d_in[12], (const float*)d_in[16], (const float*)d_in[18],
      (const float*)d_in[22], (const float*)d_in[24], (const float*)d_in[26],
      (const float*)d_in[28], (const float*)d_in[32], (const float*)d_in[34], wT);
  ln_kernel<0><<<8192, 256, 0, stream>>>(emb, c_lnkv_g, c_lnkv_b,
                                         nullptr, nullptr, lnkv_tab, nullptr);
  zinit<<<4096, 256, 0, stream>>>(inputs, emb, z);
  ln_kernel<0><<<4096, 256, 0, stream>>>(z, c_lnq_g, c_lnq_b,
                                         nullptr, nullptr, zn, nullptr);

  // ---- cross attention ---------------------------------------------------
  gemm_nt<0,false,false><<<dim3(64,8,1),256,0,stream>>>(
      lnkv_tab, nullptr, 0,0,1, 1024,
      wT + 1*MB1, nullptr, 0,0,1, 1024,
      c_bk, Ktab, 0,0,1, 1024, 1024, 1, 0);
  gemm_nt<0,false,false><<<dim3(32,8,1),256,0,stream>>>(
      zn, nullptr, 0,0,1, 1024,
      wT + 0*MB1, nullptr, 0,0,1, 1024,
      c_bq, Q, 0,0,1, 1024, 1024, 1, 0);
  for (int b = 0; b < 4; ++b) {
    // VTcb[d][s] = (gather_b(lnkv_tab) @ wv^T + bv)^T
    gemm_nt<4,true,false><<<dim3(64,8,1),256,0,stream>>>(
        lnkv_tab, inputs + (long)b*8192, 0,0,1, 1024,
        wT + 2*MB1, nullptr, 0,0,1, 1024,
        c_bv, VTcb, 0,0,1, 8192, 1024, 8192, 0);
    // scores = Q_b @ gather_b(Ktab)^T   (f32, 1024 x 8192)
    gemm_nt<3,false,true><<<dim3(8,64,1),256,0,stream>>>(
        Q + (long)b*MB1, nullptr, 0,0,1, 1024,
        Ktab, inputs + (long)b*8192, 0,0,1, 1024,
        nullptr, scores, 0,0,1, 8192, 1024, 1, 0);
    softmax_k<8192><<<1024, 256, 0, stream>>>(scores, 1023, 7168, 1.0f/32.0f);
    // split-K PV: z = K-chunk of 2048; partials f32 into Opart
    gemm_nt<3,false,false><<<dim3(8,8,4),256,0,stream>>>(
        (const u16*)scores, nullptr, 0,2048,4, 16384,
        VTcb, nullptr, 0,2048,4, 8192,
        nullptr, Opart, 1048576,0,1, 1024, 2048, 1, 0);
    reduce4<<<1024,256,0,stream>>>(Opart, O + (long)b*MB1);
  }
  // z += O @ wo^T + bo
  gemm_nt<2,false,false><<<dim3(32,8,1),256,0,stream>>>(
      O, nullptr, 0,0,1, 1024,
      wT + 3*MB1, nullptr, 0,0,1, 1024,
      c_bo, z, 0,0,1, 1024, 1024, 1, 0);

  // ---- central FFN -------------------------------------------------------
  ln_kernel<0><<<4096,256,0,stream>>>(z, c_ln2_g, c_ln2_b, nullptr,nullptr, zn, nullptr);
  gemm_nt<1,false,false><<<dim3(32,8,1),256,0,stream>>>(
      zn, nullptr, 0,0,1, 1024,
      wT + 4*MB1, nullptr, 0,0,1, 1024,
      c_b1, h1, 0,0,1, 1024, 1024, 1, 0);
  gemm_nt<2,false,false><<<dim3(32,8,1),256,0,stream>>>(
      h1, nullptr, 0,0,1, 1024,
      wT + 5*MB1, nullptr, 0,0,1, 1024,
      c_b2, z, 0,0,1, 1024, 1024, 1, 0);

  // ---- self-attention blocks (NB*L = 4, l = 0,1,0,1) ---------------------
  for (int it = 0; it < 4; ++it) {
    const int l = it & 1;
    const u16* wq = wT + (size_t)(6 + l*6 + 0)*MB1;
    const u16* wk = wT + (size_t)(6 + l*6 + 1)*MB1;
    const u16* wv = wT + (size_t)(6 + l*6 + 2)*MB1;
    const u16* wo = wT + (size_t)(6 + l*6 + 3)*MB1;
    const u16* w1 = wT + (size_t)(6 + l*6 + 4)*MB1;
    const u16* w2 = wT + (size_t)(6 + l*6 + 5)*MB1;

    ln_kernel<0><<<4096,256,0,stream>>>(z, s_lnq_g + l*1024, s_lnq_b + l*1024,
                                        nullptr,nullptr, zn, nullptr);
    gemm_nt<0,false,false><<<dim3(32,8,1),256,0,stream>>>(
        zn, nullptr, 0,0,1, 1024,  wq, nullptr, 0,0,1, 1024,
        s_bq + l*1024, Qs, 0,0,1, 1024, 1024, 1, 0);
    gemm_nt<0,false,false><<<dim3(32,8,1),256,0,stream>>>(
        zn, nullptr, 0,0,1, 1024,  wk, nullptr, 0,0,1, 1024,
        s_bk + l*1024, Ks, 0,0,1, 1024, 1024, 1, 0);
    // VsT[b][d][q]
    gemm_nt<4,false,false><<<dim3(32,8,1),256,0,stream>>>(
        zn, nullptr, 0,0,1, 1024,  wv, nullptr, 0,0,1, 1024,
        s_bv + l*1024, VsT, 0,0,1, 1024, 1024, 1024, MB1);
    // fused flash attention (replaces scores+softmax+PV)
    flash_self<<<dim3(8,32),256,0,stream>>>(Qs, Ks, VsT, O);
    gemm_nt<2,false,false><<<dim3(32,8,1),256,0,stream>>>(
        O, nullptr, 0,0,1, 1024,  wo, nullptr, 0,0,1, 1024,
        s_bo + l*1024, z, 0,0,1, 1024, 1024, 1, 0);

    ln_kernel<0><<<4096,256,0,stream>>>(z, s_ln2_g + l*1024, s_ln2_b + l*1024,
                                        nullptr,nullptr, zn, nullptr);
    gemm_nt<1,false,false><<<dim3(32,8,1),256,0,stream>>>(
        zn, nullptr, 0,0,1, 1024,  w1, nullptr, 0,0,1, 1024,
        s_b1 + l*1024, h1, 0,0,1, 1024, 1024, 1, 0);
    gemm_nt<2,false,false><<<dim3(32,8,1),256,0,stream>>>(
        h1, nullptr, 0,0,1, 1024,  w2, nullptr, 0,0,1, 1024,
        s_b2 + l*1024, z, 0,0,1, 1024, 1024, 1, 0);
  }
}

// Round 4
// 1423.349 us; speedup vs baseline: 1.6916x; 1.0877x over previous
//
#include <hip/hip_runtime.h>

typedef unsigned short u16;
typedef float f32x4 __attribute__((ext_vector_type(4)));
typedef short s16x8 __attribute__((ext_vector_type(8)));
typedef unsigned short u16x4 __attribute__((ext_vector_type(4)));

__device__ __forceinline__ u16 f2b(float x){
  union{float f; unsigned u;} a; a.f=x;
  return (u16)((a.u + 0x7fffu + ((a.u>>16)&1u))>>16);
}

__device__ __forceinline__ float block_reduce(float v, int op, float* sh){
  #pragma unroll
  for (int o=32;o>0;o>>=1){
    float t = __shfl_down(v, o);
    v = op ? fmaxf(v,t) : v+t;
  }
  int w = threadIdx.x>>6;
  if ((threadIdx.x&63)==0) sh[w]=v;
  __syncthreads();
  float r = op ? fmaxf(fmaxf(sh[0],sh[1]),fmaxf(sh[2],sh[3]))
               : (sh[0]+sh[1]+sh[2]+sh[3]);
  __syncthreads();
  return r;
}

// ---------------------------------------------------------------------------
// NT GEMM: C[m][n] = sum_k A[m][k] * B[n][k]  (+bias[n]) with optional row
// gather on A and/or B. Tiles 128x128, BK=64, 256 threads (4 waves).
// EPI: 0 = bf16 store, 1 = sqrelu->bf16, 2 = f32 residual +=, 3 = f32 store,
//      4 = transposed bf16 store: C[(m/mb)*cbatch + n*ldc + m%mb]
// ---------------------------------------------------------------------------
template<int EPI, bool AG, bool BG>
__global__ __launch_bounds__(256)
void gemm_nt(const u16* __restrict__ A, const int* __restrict__ aidx,
             long a_s1, long a_s2, int azd, int lda,
             const u16* __restrict__ B, const int* __restrict__ bidx,
             long b_s1, long b_s2, int bzd, int ldb,
             const float* __restrict__ bias,
             void* __restrict__ Cv, long c_s1, long c_s2, int czd, int ldc,
             int K, int mb, long cbatch)
{
  __shared__ u16 lA[128][72];
  __shared__ u16 lB[128][72];
  const int tid = threadIdx.x;
  const int z = blockIdx.z;
  const int m0 = blockIdx.x * 128;
  const int n0 = blockIdx.y * 128;
  const u16* Ab = A + (long)(z/azd)*a_s1 + (long)(z%azd)*a_s2;
  const u16* Bb = B + (long)(z/bzd)*b_s1 + (long)(z%bzd)*b_s2;

  const int w = tid >> 6, lane = tid & 63;
  const int wr = w >> 1, wc = w & 1;
  const int lm = lane >> 4, ln = lane & 15;

  f32x4 acc[4][4];
  #pragma unroll
  for (int i=0;i<4;i++)
    #pragma unroll
    for (int j=0;j<4;j++) acc[i][j] = (f32x4){0.f,0.f,0.f,0.f};

  for (int kt = 0; kt < K; kt += 64) {
    __syncthreads();
    #pragma unroll
    for (int i = 0; i < 4; i++) {
      int c = tid + i*256;
      int r = c >> 3, kc = (c & 7) << 3;
      long arow = AG ? (long)aidx[m0 + r] : (long)(m0 + r);
      s16x8 va = *(const s16x8*)(Ab + arow*(long)lda + kt + kc);
      *(s16x8*)(&lA[r][kc]) = va;
      long brow = BG ? (long)bidx[n0 + r] : (long)(n0 + r);
      s16x8 vb = *(const s16x8*)(Bb + brow*(long)ldb + kt + kc);
      *(s16x8*)(&lB[r][kc]) = vb;
    }
    __syncthreads();
    #pragma unroll
    for (int kk = 0; kk < 2; kk++) {
      const int ks = kk*32 + lm*8;
      s16x8 af[4], bf[4];
      #pragma unroll
      for (int i=0;i<4;i++) af[i] = *(const s16x8*)(&lA[wr*64 + i*16 + ln][ks]);
      #pragma unroll
      for (int j=0;j<4;j++) bf[j] = *(const s16x8*)(&lB[wc*64 + j*16 + ln][ks]);
      #pragma unroll
      for (int i=0;i<4;i++)
        #pragma unroll
        for (int j=0;j<4;j++)
          acc[i][j] = __builtin_amdgcn_mfma_f32_16x16x32_bf16(af[i], bf[j], acc[i][j], 0,0,0);
    }
  }

  const long co = (long)(z/czd)*c_s1 + (long)(z%czd)*c_s2;
  #pragma unroll
  for (int i=0;i<4;i++) {
    const int gmb = m0 + wr*64 + i*16 + lm*4;
    #pragma unroll
    for (int j=0;j<4;j++) {
      const int gn = n0 + wc*64 + j*16 + ln;
      float bb = 0.f;
      if constexpr (EPI != 3) { if (bias) bb = bias[gn]; }
      f32x4 v = acc[i][j];
      if constexpr (EPI == 4) {
        long addr = co + (long)(gmb/mb)*cbatch + (long)gn*ldc + (gmb%mb);
        u16x4 pk;
        #pragma unroll
        for (int r=0;r<4;r++) pk[r] = f2b(v[r] + bb);
        *(u16x4*)((u16*)Cv + addr) = pk;
      } else if constexpr (EPI == 2) {
        float* Cf = (float*)Cv;
        #pragma unroll
        for (int r=0;r<4;r++) {
          long idx = co + (long)(gmb+r)*ldc + gn;
          Cf[idx] += v[r] + bb;
        }
      } else if constexpr (EPI == 3) {
        float* Cf = (float*)Cv;
        #pragma unroll
        for (int r=0;r<4;r++) Cf[co + (long)(gmb+r)*ldc + gn] = v[r];
      } else {
        u16* Cb = (u16*)Cv;
        #pragma unroll
        for (int r=0;r<4;r++) {
          float x = v[r] + bb;
          if constexpr (EPI == 1) { x = x > 0.f ? x*x : 0.f; }
          Cb[co + (long)(gmb+r)*ldc + gn] = f2b(x);
        }
      }
    }
  }
}

// ---------------------------------------------------------------------------
// Fused QKV projection: A = zn (4096x1024), B = wT[wq|wk|wv] (3072x1024).
// Columns 0..1023 -> Qs, 1024..2047 -> Ks, 2048..3071 -> VsT (transposed:
// VsT[(row>>10)*1M + d*1024 + row&1023]). bias = concat 3072.
// Grid (32, 24) = 768 blocks (3 blocks/CU).
// ---------------------------------------------------------------------------
__global__ __launch_bounds__(256)
void gemm_qkv(const u16* __restrict__ A, const u16* __restrict__ Bw,
              const float* __restrict__ bias,
              u16* __restrict__ Qs, u16* __restrict__ Ks, u16* __restrict__ VsT)
{
  __shared__ u16 lA[128][72];
  __shared__ u16 lB[128][72];
  const int tid = threadIdx.x;
  const int m0 = blockIdx.x * 128;
  const int n0 = blockIdx.y * 128;
  const int w = tid >> 6, lane = tid & 63;
  const int wr = w >> 1, wc = w & 1;
  const int lm = lane >> 4, ln = lane & 15;

  f32x4 acc[4][4];
  #pragma unroll
  for (int i=0;i<4;i++)
    #pragma unroll
    for (int j=0;j<4;j++) acc[i][j] = (f32x4){0.f,0.f,0.f,0.f};

  for (int kt = 0; kt < 1024; kt += 64) {
    __syncthreads();
    #pragma unroll
    for (int i = 0; i < 4; i++) {
      int c = tid + i*256;
      int r = c >> 3, kc = (c & 7) << 3;
      *(s16x8*)(&lA[r][kc]) = *(const s16x8*)(A + (long)(m0+r)*1024 + kt + kc);
      *(s16x8*)(&lB[r][kc]) = *(const s16x8*)(Bw + (long)(n0+r)*1024 + kt + kc);
    }
    __syncthreads();
    #pragma unroll
    for (int kk = 0; kk < 2; kk++) {
      const int ks = kk*32 + lm*8;
      s16x8 af[4], bf[4];
      #pragma unroll
      for (int i=0;i<4;i++) af[i] = *(const s16x8*)(&lA[wr*64 + i*16 + ln][ks]);
      #pragma unroll
      for (int j=0;j<4;j++) bf[j] = *(const s16x8*)(&lB[wc*64 + j*16 + ln][ks]);
      #pragma unroll
      for (int i=0;i<4;i++)
        #pragma unroll
        for (int j=0;j<4;j++)
          acc[i][j] = __builtin_amdgcn_mfma_f32_16x16x32_bf16(af[i], bf[j], acc[i][j], 0,0,0);
    }
  }

  #pragma unroll
  for (int i=0;i<4;i++) {
    const int gmb = m0 + wr*64 + i*16 + lm*4;
    #pragma unroll
    for (int j=0;j<4;j++) {
      const int gn = n0 + wc*64 + j*16 + ln;
      const float bb = bias[gn];
      f32x4 v = acc[i][j];
      if (gn < 2048) {
        u16* dst = (gn < 1024) ? Qs : Ks;
        const int col = gn & 1023;
        #pragma unroll
        for (int r=0;r<4;r++) dst[(long)(gmb+r)*1024 + col] = f2b(v[r] + bb);
      } else {
        long addr = (long)(gmb >> 10)*1048576 + (long)(gn - 2048)*1024 + (gmb & 1023);
        u16x4 pk;
        #pragma unroll
        for (int r=0;r<4;r++) pk[r] = f2b(v[r] + bb);
        *(u16x4*)(VsT + addr) = pk;
      }
    }
  }
}

// ---------------------------------------------------------------------------
// Flash self-attention: causal, H=8, d=128, Z=1024 per batch.
// Grid (bh=32, 16 q-tiles of 64 rows) = 512 blocks (2/CU). blockIdx.x=bh so
// id%8=h -> one head's K/V stays in one XCD L2. q-tile remap puts long
// (high-qt) blocks first and pairs work to ~17 kv-tiles per CU.
// 4 waves; wave owns 16 q-rows. S^T = K*Q^T per 64-row KV tile (softmax is
// per-lane over regs + 2 shfl), P via per-wave swizzled LDS, PV uses V^T.
// ---------------------------------------------------------------------------
__global__ __launch_bounds__(256)
void flash_self(const u16* __restrict__ Qs, const u16* __restrict__ Ks,
                const u16* __restrict__ VsT, u16* __restrict__ O)
{
  __shared__ u16 lK[64][128];    // [kk][d], 16B-chunk XOR swizzle
  __shared__ u16 lV[128][64];    // [d][kk], swizzled
  __shared__ u16 lP[4][16][64];  // per-wave [q][kk], swizzled

  const int tid = threadIdx.x;
  const int w = tid >> 6, lane = tid & 63;
  const int g = lane >> 4, ln = lane & 15;
  const int bh = blockIdx.x;
  const int b = bh >> 3, h = bh & 7;
  const int y = blockIdx.y;
  const int qt = (y < 8) ? (15 - y) : (y - 8);   // longest-first + pairing

  const long qrow0 = (long)b*1024 + qt*64 + w*16;
  const u16* Qp = Qs + qrow0*1024 + h*128;
  const u16* Kp = Ks + (long)b*1048576 + h*128;
  const u16* Vp = VsT + (long)b*1048576 + (long)h*131072;

  // Q as B-operand frags: n=q=ln, k(d) = 32*ks + 8*g + j
  s16x8 bq[4];
  #pragma unroll
  for (int ks=0;ks<4;ks++)
    bq[ks] = *(const s16x8*)(Qp + (long)ln*1024 + ks*32 + g*8);

  f32x4 ao[8];                   // O^T acc: row d=16mi+4g+r, col q=ln
  #pragma unroll
  for (int i=0;i<8;i++) ao[i] = (f32x4){0.f,0.f,0.f,0.f};
  float mrun = -3.0e38f, lrun = 0.f;
  const int qc = qt*64 + w*16 + ln;

  const int nt = qt + 1;
  for (int kt = 0; kt < nt; ++kt) {
    __syncthreads();
    {
      const u16* src = Kp + (long)(kt*64)*1024;
      #pragma unroll
      for (int i=0;i<4;i++){
        int c = i*256 + tid;
        int rr = c >> 4, d8 = c & 15;
        s16x8 v = *(const s16x8*)(src + (long)rr*1024 + d8*8);
        *(s16x8*)(&lK[rr][(d8 ^ (rr&7))*8]) = v;
      }
      const u16* vsrc = Vp + kt*64;
      #pragma unroll
      for (int i=0;i<4;i++){
        int c = i*256 + tid;
        int dd = c >> 3, k8 = c & 7;
        s16x8 v = *(const s16x8*)(vsrc + (long)dd*1024 + k8*8);
        *(s16x8*)(&lV[dd][(k8 ^ (dd&7))*8]) = v;
      }
    }
    __syncthreads();

    // S^T tile: rows kk (4 frags), col q (1 frag)
    f32x4 as_[4];
    #pragma unroll
    for (int i=0;i<4;i++) as_[i] = (f32x4){0.f,0.f,0.f,0.f};
    #pragma unroll
    for (int ks=0;ks<4;ks++){
      #pragma unroll
      for (int mi=0;mi<4;mi++){
        s16x8 ak = *(const s16x8*)(&lK[16*mi + ln][((g + 4*ks) ^ (ln&7))*8]);
        as_[mi] = __builtin_amdgcn_mfma_f32_16x16x32_bf16(ak, bq[ks], as_[mi], 0,0,0);
      }
    }

    // online softmax per q-column (per lane + cross-g shfl)
    const int kkb = kt*64 + 4*g;
    float mx = -3.0e38f;
    #pragma unroll
    for (int mi=0;mi<4;mi++)
      #pragma unroll
      for (int r=0;r<4;r++){
        float s = as_[mi][r] * 0.08838834764831845f;
        if (kkb + 16*mi + r > qc) s = -3.0e38f;
        as_[mi][r] = s;
        mx = fmaxf(mx, s);
      }
    mx = fmaxf(mx, __shfl_xor(mx, 16));
    mx = fmaxf(mx, __shfl_xor(mx, 32));
    float mnew = fmaxf(mrun, mx);
    float alpha = __expf(mrun - mnew);
    float sum = 0.f;
    #pragma unroll
    for (int mi=0;mi<4;mi++){
      u16x4 pk;
      #pragma unroll
      for (int r=0;r<4;r++){
        float p = __expf(as_[mi][r] - mnew);
        sum += p;
        pk[r] = f2b(p);
      }
      // P[q][kk]: q=ln, kk=16mi+4g..+3 ; 16B-granule swizzle by q&7
      *(u16x4*)(&lP[w][ln][(((2*mi + (g>>1)) ^ (ln&7))<<3) + (g&1)*4]) = pk;
    }
    sum += __shfl_xor(sum, 16);
    sum += __shfl_xor(sum, 32);
    lrun = lrun*alpha + sum;
    mrun = mnew;
    #pragma unroll
    for (int mi=0;mi<8;mi++)
      #pragma unroll
      for (int r=0;r<4;r++)
        ao[mi][r] *= alpha;

    // O^T += V^T · P^T  (A from lV, B from lP)
    #pragma unroll
    for (int ks=0;ks<2;ks++){
      s16x8 bp = *(const s16x8*)(&lP[w][ln][((4*ks + g) ^ (ln&7))*8]);
      #pragma unroll
      for (int mi=0;mi<8;mi++){
        s16x8 av = *(const s16x8*)(&lV[16*mi + ln][((g + 4*ks) ^ (ln&7))*8]);
        ao[mi] = __builtin_amdgcn_mfma_f32_16x16x32_bf16(av, bp, ao[mi], 0,0,0);
      }
    }
  }

  const float inv = 1.f/lrun;
  #pragma unroll
  for (int mi=0;mi<8;mi++){
    u16x4 pk;
    #pragma unroll
    for (int r=0;r<4;r++) pk[r] = f2b(ao[mi][r]*inv);
    *(u16x4*)(O + (qrow0 + ln)*1024 + h*128 + 16*mi + 4*g) = pk;
  }
}

// ---------------------------------------------------------------------------
// Sum 4 split-K partial planes (f32, 1M elems each) -> bf16.
// ---------------------------------------------------------------------------
__global__ __launch_bounds__(256)
void reduce4(const float* __restrict__ Pp, u16* __restrict__ Ob){
  long i = ((long)blockIdx.x*256 + threadIdx.x)*4;
  f32x4 a = *(const f32x4*)(Pp + i);
  f32x4 b = *(const f32x4*)(Pp + 1048576 + i);
  f32x4 c = *(const f32x4*)(Pp + 2097152 + i);
  f32x4 d = *(const f32x4*)(Pp + 3145728 + i);
  u16x4 pk;
  #pragma unroll
  for (int r=0;r<4;r++) pk[r] = f2b(a[r]+b[r]+c[r]+d[r]);
  *(u16x4*)(Ob + i) = pk;
}

// ---------------------------------------------------------------------------
// LayerNorm of a 1024-wide f32 row -> bf16.
// ---------------------------------------------------------------------------
template<int TWO>
__global__ __launch_bounds__(256)
void ln_kernel(const float* __restrict__ X,
               const float* __restrict__ g1, const float* __restrict__ bb1,
               const float* __restrict__ g2, const float* __restrict__ bb2,
               u16* __restrict__ o1, u16* __restrict__ o2)
{
  __shared__ float sh[4];
  const long row = blockIdx.x;
  const int tid = threadIdx.x;
  const float* x = X + row*1024;
  float4 t = *(const float4*)(x + tid*4);
  float s = t.x+t.y+t.z+t.w;
  float m = block_reduce(s, 0, sh) * (1.f/1024.f);
  float d0=t.x-m, d1=t.y-m, d2=t.z-m, d3=t.w-m;
  float s2 = d0*d0+d1*d1+d2*d2+d3*d3;
  float var = block_reduce(s2, 0, sh) * (1.f/1024.f);
  float r = rsqrtf(var + 1e-5f);
  const int c = tid*4;
  {
    float4 g = *(const float4*)(g1+c);
    float4 b = *(const float4*)(bb1+c);
    u16x4 pk;
    pk[0]=f2b(d0*r*g.x+b.x); pk[1]=f2b(d1*r*g.y+b.y);
    pk[2]=f2b(d2*r*g.z+b.z); pk[3]=f2b(d3*r*g.w+b.w);
    *(u16x4*)(o1 + row*1024 + c) = pk;
  }
  if constexpr (TWO) {
    float4 g = *(const float4*)(g2+c);
    float4 b = *(const float4*)(bb2+c);
    u16x4 pk;
    pk[0]=f2b(d0*r*g.x+b.x); pk[1]=f2b(d1*r*g.y+b.y);
    pk[2]=f2b(d2*r*g.z+b.z); pk[3]=f2b(d3*r*g.w+b.w);
    *(u16x4*)(o2 + row*1024 + c) = pk;
  }
}

// ---------------------------------------------------------------------------
// Masked softmax over a row of LEN f32 scores; writes bf16 P in place.
// ---------------------------------------------------------------------------
template<int LEN>
__global__ __launch_bounds__(256)
void softmax_k(float* __restrict__ S, int qmask, int off, float scale)
{
  constexpr int PER = LEN/256;
  __shared__ float sh[4];
  const long row = blockIdx.x;
  const int qi = ((int)row) & qmask;
  const int lim = off + qi;
  float* srow = S + row*(long)LEN;
  const int tid = threadIdx.x;
  float v[PER];
  float mx = -3.0e38f;
  #pragma unroll
  for (int i=0;i<PER/4;i++){
    int j0 = i*1024 + tid*4;
    float4 t = *(const float4*)(srow + j0);
    float tv[4] = {t.x,t.y,t.z,t.w};
    #pragma unroll
    for (int k=0;k<4;k++){
      float val = (j0+k <= lim) ? tv[k]*scale : -3.0e38f;
      v[i*4+k] = val;
      mx = fmaxf(mx, val);
    }
  }
  float M = block_reduce(mx, 1, sh);
  float s = 0.f;
  #pragma unroll
  for (int i=0;i<PER;i++){ float e = __expf(v[i]-M); v[i]=e; s+=e; }
  float T = block_reduce(s, 0, sh);
  float inv = 1.0f / T;
  u16* p = (u16*)srow;
  #pragma unroll
  for (int i=0;i<PER/4;i++){
    int j0 = i*1024 + tid*4;
    u16x4 pk;
    #pragma unroll
    for (int k=0;k<4;k++) pk[k] = f2b(v[i*4+k]*inv);
    *(u16x4*)(p + j0) = pk;
  }
}

// ---------------------------------------------------------------------------
__global__ __launch_bounds__(256)
void zinit(const int* __restrict__ inputs, const float* __restrict__ emb,
           float* __restrict__ z)
{
  const int row = blockIdx.x;            // 0..4095
  const int b = row >> 10, q = row & 1023;
  const int id = inputs[(long)b*8192 + 7168 + q];
  float4 v = *(const float4*)(emb + (long)id*1024 + threadIdx.x*4);
  *(float4*)(z + (long)row*1024 + threadIdx.x*4) = v;
}

// ---------------------------------------------------------------------------
// Concat self-attn QKV biases: qkvb[l][3072] = [s_bq[l] | s_bk[l] | s_bv[l]]
// ---------------------------------------------------------------------------
__global__ __launch_bounds__(256)
void pack_bias(const float* __restrict__ bq, const float* __restrict__ bk,
               const float* __restrict__ bv, float* __restrict__ qkvb)
{
  const int l = blockIdx.y;
  const int i = blockIdx.x*256 + threadIdx.x;   // 0..3071
  float v;
  if (i < 1024)      v = bq[l*1024 + i];
  else if (i < 2048) v = bk[l*1024 + i - 1024];
  else               v = bv[l*1024 + i - 2048];
  qkvb[l*3072 + i] = v;
}

// ---------------------------------------------------------------------------
__global__ __launch_bounds__(256)
void transpose_w(const float* cwq, const float* cwk, const float* cwv,
                 const float* cwo, const float* cw1, const float* cw2,
                 const float* swq, const float* swk, const float* swv,
                 const float* swo, const float* sw1, const float* sw2,
                 u16* __restrict__ wT)
{
  const int slot = blockIdx.z;
  const float* W;
  switch (slot) {
    case 0:  W = cwq; break;  case 1:  W = cwk; break;
    case 2:  W = cwv; break;  case 3:  W = cwo; break;
    case 4:  W = cw1; break;  case 5:  W = cw2; break;
    case 6:  W = swq; break;  case 7:  W = swk; break;
    case 8:  W = swv; break;  case 9:  W = swo; break;
    case 10: W = sw1; break;  case 11: W = sw2; break;
    case 12: W = swq + 1048576; break; case 13: W = swk + 1048576; break;
    case 14: W = swv + 1048576; break; case 15: W = swo + 1048576; break;
    case 16: W = sw1 + 1048576; break; default: W = sw2 + 1048576; break;
  }
  u16* T = wT + (long)slot*1048576;
  __shared__ float t[32][33];
  const int tx = threadIdx.x & 31, ty = threadIdx.x >> 5;   // 32 x 8
  const int k0 = blockIdx.x*32, n0 = blockIdx.y*32;
  #pragma unroll
  for (int i=0;i<4;i++)
    t[ty + i*8][tx] = W[(long)(k0 + ty + i*8)*1024 + n0 + tx];
  __syncthreads();
  #pragma unroll
  for (int i=0;i<4;i++)
    T[(long)(n0 + ty + i*8)*1024 + k0 + tx] = f2b(t[tx][ty + i*8]);
}

// ---------------------------------------------------------------------------
extern "C" void kernel_launch(void* const* d_in, const int* in_sizes, int n_in,
                              void* d_out, int out_size, void* d_ws, size_t ws_size,
                              hipStream_t stream)
{
  (void)in_sizes; (void)n_in; (void)out_size;
  const int*   inputs   = (const int*)  d_in[0];
  const float* emb      = (const float*)d_in[1];
  const float* c_lnq_g  = (const float*)d_in[2];
  const float* c_lnq_b  = (const float*)d_in[3];
  const float* c_lnkv_g = (const float*)d_in[4];
  const float* c_lnkv_b = (const float*)d_in[5];
  const float* c_bq = (const float*)d_in[7];
  const float* c_bk = (const float*)d_in[9];
  const float* c_bv = (const float*)d_in[11];
  const float* c_bo = (const float*)d_in[13];
  const float* c_ln2_g = (const float*)d_in[14];
  const float* c_ln2_b = (const float*)d_in[15];
  const float* c_b1 = (const float*)d_in[17];
  const float* c_b2 = (const float*)d_in[19];
  const float* s_lnq_g = (const float*)d_in[20];
  const float* s_lnq_b = (const float*)d_in[21];
  const float* s_bq = (const float*)d_in[23];
  const float* s_bk = (const float*)d_in[25];
  const float* s_bv = (const float*)d_in[27];
  const float* s_bo = (const float*)d_in[29];
  const float* s_ln2_g = (const float*)d_in[30];
  const float* s_ln2_b = (const float*)d_in[31];
  const float* s_b1 = (const float*)d_in[33];
  const float* s_b2 = (const float*)d_in[35];

  const long MB1 = 1048576;

  char* wsb = (char*)d_ws;
  size_t off = 0;
  auto alloc = [&](size_t n)->char* {
    char* p = wsb + off; off += (n + 255) & ~(size_t)255; return p;
  };
  u16*   wT       = (u16*)  alloc((size_t)18*1048576*2);   // 36 MB
  u16*   lnkv_tab = (u16*)  alloc((size_t)8192*1024*2);    // 16 MB
  u16*   Ktab     = (u16*)  alloc((size_t)8192*1024*2);    // 16 MB
  u16*   VTcb     = (u16*)  alloc((size_t)1024*8192*2);    // 16 MB (per-b, reused)
  u16*   Q        = (u16*)  alloc((size_t)4096*1024*2);    // 8 MB
  u16*   zn       = (u16*)  alloc((size_t)4096*1024*2);
  u16*   h1       = (u16*)  alloc((size_t)4096*1024*2);
  u16*   O        = (u16*)  alloc((size_t)4096*1024*2);
  u16*   Qs       = (u16*)  alloc((size_t)4096*1024*2);    // 8 MB  (also Opart lo)
  u16*   Ks       = (u16*)  alloc((size_t)4096*1024*2);    // 8 MB  (also Opart hi)
  u16*   VsT      = (u16*)  alloc((size_t)4096*1024*2);
  float* scores   = (float*)alloc((size_t)8*1024*1024*4);  // 32 MB (reused)
  float* qkvb     = (float*)alloc((size_t)2*3072*4);
  float* Opart    = (float*)Qs;   // 16 MB alias over Qs+Ks (dead during cross)
  float* z        = (float*)d_out;

  if (ws_size < off) return;  // ws too small: leave output zeroed (diagnostic)

  // ---- setup -------------------------------------------------------------
  transpose_w<<<dim3(32,32,18), 256, 0, stream>>>(
      (const float*)d_in[6], (const float*)d_in[8], (const float*)d_in[10],
      (const float*)d_in[12], (const float*)d_in[16], (const float*)d_in[18],
      (const float*)d_in[22], (const float*)d_in[24], (const float*)d_in[26],
      (const float*)d_in[28], (const float*)d_in[32], (const float*)d_in[34], wT);
  pack_bias<<<dim3(12,2), 256, 0, stream>>>(s_bq, s_bk, s_bv, qkvb);
  ln_kernel<0><<<8192, 256, 0, stream>>>(emb, c_lnkv_g, c_lnkv_b,
                                         nullptr, nullptr, lnkv_tab, nullptr);
  zinit<<<4096, 256, 0, stream>>>(inputs, emb, z);
  ln_kernel<0><<<4096, 256, 0, stream>>>(z, c_lnq_g, c_lnq_b,
                                         nullptr, nullptr, zn, nullptr);

  // ---- cross attention ---------------------------------------------------
  gemm_nt<0,false,false><<<dim3(64,8,1),256,0,stream>>>(
      lnkv_tab, nullptr, 0,0,1, 1024,
      wT + 1*MB1, nullptr, 0,0,1, 1024,
      c_bk, Ktab, 0,0,1, 1024, 1024, 1, 0);
  gemm_nt<0,false,false><<<dim3(32,8,1),256,0,stream>>>(
      zn, nullptr, 0,0,1, 1024,
      wT + 0*MB1, nullptr, 0,0,1, 1024,
      c_bq, Q, 0,0,1, 1024, 1024, 1, 0);
  for (int b = 0; b < 4; ++b) {
    // VTcb[d][s] = (gather_b(lnkv_tab) @ wv^T + bv)^T
    gemm_nt<4,true,false><<<dim3(64,8,1),256,0,stream>>>(
        lnkv_tab, inputs + (long)b*8192, 0,0,1, 1024,
        wT + 2*MB1, nullptr, 0,0,1, 1024,
        c_bv, VTcb, 0,0,1, 8192, 1024, 8192, 0);
    // scores = Q_b @ gather_b(Ktab)^T   (f32, 1024 x 8192)
    gemm_nt<3,false,true><<<dim3(8,64,1),256,0,stream>>>(
        Q + (long)b*MB1, nullptr, 0,0,1, 1024,
        Ktab, inputs + (long)b*8192, 0,0,1, 1024,
        nullptr, scores, 0,0,1, 8192, 1024, 1, 0);
    softmax_k<8192><<<1024, 256, 0, stream>>>(scores, 1023, 7168, 1.0f/32.0f);
    // split-K PV: z = K-chunk of 2048; partials f32 into Opart
    gemm_nt<3,false,false><<<dim3(8,8,4),256,0,stream>>>(
        (const u16*)scores, nullptr, 0,2048,4, 16384,
        VTcb, nullptr, 0,2048,4, 8192,
        nullptr, Opart, 1048576,0,1, 1024, 2048, 1, 0);
    reduce4<<<1024,256,0,stream>>>(Opart, O + (long)b*MB1);
  }
  // z += O @ wo^T + bo
  gemm_nt<2,false,false><<<dim3(32,8,1),256,0,stream>>>(
      O, nullptr, 0,0,1, 1024,
      wT + 3*MB1, nullptr, 0,0,1, 1024,
      c_bo, z, 0,0,1, 1024, 1024, 1, 0);

  // ---- central FFN -------------------------------------------------------
  ln_kernel<0><<<4096,256,0,stream>>>(z, c_ln2_g, c_ln2_b, nullptr,nullptr, zn, nullptr);
  gemm_nt<1,false,false><<<dim3(32,8,1),256,0,stream>>>(
      zn, nullptr, 0,0,1, 1024,
      wT + 4*MB1, nullptr, 0,0,1, 1024,
      c_b1, h1, 0,0,1, 1024, 1024, 1, 0);
  gemm_nt<2,false,false><<<dim3(32,8,1),256,0,stream>>>(
      h1, nullptr, 0,0,1, 1024,
      wT + 5*MB1, nullptr, 0,0,1, 1024,
      c_b2, z, 0,0,1, 1024, 1024, 1, 0);

  // ---- self-attention blocks (NB*L = 4, l = 0,1,0,1) ---------------------
  for (int it = 0; it < 4; ++it) {
    const int l = it & 1;
    const u16* wqkv = wT + (size_t)(6 + l*6)*MB1;       // wq|wk|wv contiguous
    const u16* wo = wT + (size_t)(6 + l*6 + 3)*MB1;
    const u16* w1 = wT + (size_t)(6 + l*6 + 4)*MB1;
    const u16* w2 = wT + (size_t)(6 + l*6 + 5)*MB1;

    ln_kernel<0><<<4096,256,0,stream>>>(z, s_lnq_g + l*1024, s_lnq_b + l*1024,
                                        nullptr,nullptr, zn, nullptr);
    // fused QKV projection (768 blocks, 3/CU)
    gemm_qkv<<<dim3(32,24),256,0,stream>>>(zn, wqkv, qkvb + l*3072, Qs, Ks, VsT);
    // fused flash attention
    flash_self<<<dim3(32,16),256,0,stream>>>(Qs, Ks, VsT, O);
    gemm_nt<2,false,false><<<dim3(32,8,1),256,0,stream>>>(
        O, nullptr, 0,0,1, 1024,  wo, nullptr, 0,0,1, 1024,
        s_bo + l*1024, z, 0,0,1, 1024, 1024, 1, 0);

    ln_kernel<0><<<4096,256,0,stream>>>(z, s_ln2_g + l*1024, s_ln2_b + l*1024,
                                        nullptr,nullptr, zn, nullptr);
    gemm_nt<1,false,false><<<dim3(32,8,1),256,0,stream>>>(
        zn, nullptr, 0,0,1, 1024,  w1, nullptr, 0,0,1, 1024,
        s_b1 + l*1024, h1, 0,0,1, 1024, 1024, 1, 0);
    gemm_nt<2,false,false><<<dim3(32,8,1),256,0,stream>>>(
        h1, nullptr, 0,0,1, 1024,  w2, nullptr, 0,0,1, 1024,
        s_b2 + l*1024, z, 0,0,1, 1024, 1024, 1, 0);
  }
}